// Round 1
// baseline (612.059 us; speedup 1.0000x reference)
//
#include <hip/hip_runtime.h>

// DSBatchNorm2: per-domain batchnorm (training mode), D=8 domains,
// x [65536,1024] f32, y [65536] int domain ids, gamma/beta [1024] f32.
//
// Pass 1 (stats): per-(d,f) sum / sumsq / count via register accumulation +
//   LDS reduce + global f32 atomics.
// Pass 2 (prep): fold mean/var/gamma/beta/count-select into per-(d,f)
//   scale & bias:  out = x*scale + bias.
//     count>1 : scale = gamma/sqrt(var+eps), bias = beta - mean*scale
//     count==1: scale = 1, bias = 0   (reference returns raw x)
//     count==0: scale = 0, bias = 0
// Pass 3 (norm): streaming fma, float4.

#define BATCH 65536
#define NFEAT 1024
#define NF4   256        // float4s per row
#define NDOM  8
#define EPSV  1e-5f

// ws layout in floats:
#define WS_SUM   0            // [8][1024] f32
#define WS_SQ    8192         // [8][1024] f32
#define WS_CNT   16384        // [8] u32
#define WS_SCL   16392        // [8][1024] f32 (byte off 65568, 16B aligned)
#define WS_BIA   24584        // [8][1024] f32 (byte off 98336, 16B aligned)
#define WS_ZERO_BYTES ((16384 + 8) * 4)   // zero sum+sq+cnt each call

__global__ __launch_bounds__(256) void dsbn_stats(
    const float* __restrict__ x, const int* __restrict__ y,
    float* __restrict__ gsum, float* __restrict__ gsq,
    unsigned* __restrict__ gcnt)
{
  __shared__ float lsum[NDOM][NF4];   // 8 KiB
  __shared__ float lsq [NDOM][NF4];   // 8 KiB
  __shared__ unsigned lcnt[NDOM];

  const int tid    = threadIdx.x;
  const int w      = tid >> 6;             // wave 0..3
  const int lane   = tid & 63;
  const int ftile  = blockIdx.x & 3;       // which 256-feature tile
  const int rowgrp = blockIdx.x >> 2;      // 0..255
  const int gw     = rowgrp * 4 + w;       // global wave id 0..1023
  const int c4     = ftile * 64 + lane;    // float4 column in row, 0..255

  for (int j = tid; j < NDOM * NF4; j += 256) {
    (&lsum[0][0])[j] = 0.f;
    (&lsq [0][0])[j] = 0.f;
  }
  if (tid < NDOM) lcnt[tid] = 0u;
  __syncthreads();

  float4 s[NDOM], q[NDOM];
  int cnt[NDOM];
#pragma unroll
  for (int dd = 0; dd < NDOM; ++dd) {
    s[dd] = make_float4(0.f, 0.f, 0.f, 0.f);
    q[dd] = make_float4(0.f, 0.f, 0.f, 0.f);
    cnt[dd] = 0;
  }

  const float4* __restrict__ x4 = reinterpret_cast<const float4*>(x);
  const int r0 = gw * 64;   // each wave owns 64 consecutive rows

  // switch on wave-uniform scalar d keeps register indices compile-time
  // (rule #20) and compiles to scalar-branch accumulation (~9 VALU / 16B).
#define DSBN_ADD(dd, v)                                  \
  { s[dd].x += (v).x; s[dd].y += (v).y;                  \
    s[dd].z += (v).z; s[dd].w += (v).w;                  \
    q[dd].x = fmaf((v).x, (v).x, q[dd].x);               \
    q[dd].y = fmaf((v).y, (v).y, q[dd].y);               \
    q[dd].z = fmaf((v).z, (v).z, q[dd].z);               \
    q[dd].w = fmaf((v).w, (v).w, q[dd].w);               \
    cnt[dd]++; }

#define DSBN_ACC(d, v)                                   \
  switch (d) {                                           \
    case 0: DSBN_ADD(0, v); break;                       \
    case 1: DSBN_ADD(1, v); break;                       \
    case 2: DSBN_ADD(2, v); break;                       \
    case 3: DSBN_ADD(3, v); break;                       \
    case 4: DSBN_ADD(4, v); break;                       \
    case 5: DSBN_ADD(5, v); break;                       \
    case 6: DSBN_ADD(6, v); break;                       \
    default: DSBN_ADD(7, v); break;                      \
  }

#pragma unroll 1
  for (int k = 0; k < 64; k += 4) {     // 4-row unroll for MLP of loads
    const int ra = r0 + k;
    float4 va = x4[(size_t)(ra    ) * NF4 + c4];
    float4 vb = x4[(size_t)(ra + 1) * NF4 + c4];
    float4 vc = x4[(size_t)(ra + 2) * NF4 + c4];
    float4 vd = x4[(size_t)(ra + 3) * NF4 + c4];
    int da = __builtin_amdgcn_readfirstlane(y[ra    ]);
    int db = __builtin_amdgcn_readfirstlane(y[ra + 1]);
    int dc = __builtin_amdgcn_readfirstlane(y[ra + 2]);
    int de = __builtin_amdgcn_readfirstlane(y[ra + 3]);
    DSBN_ACC(da, va);
    DSBN_ACC(db, vb);
    DSBN_ACC(dc, vc);
    DSBN_ACC(de, vd);
  }

  // cross-wave reduce: 4 waves hit the same LDS cells -> DS atomics
#pragma unroll
  for (int dd = 0; dd < NDOM; ++dd) {
    const int j0 = lane * 4;
    atomicAdd(&lsum[dd][j0 + 0], s[dd].x);
    atomicAdd(&lsum[dd][j0 + 1], s[dd].y);
    atomicAdd(&lsum[dd][j0 + 2], s[dd].z);
    atomicAdd(&lsum[dd][j0 + 3], s[dd].w);
    atomicAdd(&lsq [dd][j0 + 0], q[dd].x);
    atomicAdd(&lsq [dd][j0 + 1], q[dd].y);
    atomicAdd(&lsq [dd][j0 + 2], q[dd].z);
    atomicAdd(&lsq [dd][j0 + 3], q[dd].w);
  }
  // counts: each row is visited by all 4 ftiles; only ftile 0 counts.
  // per-lane counters are wave-uniform, so one lane per wave contributes.
  if (ftile == 0 && lane == 0) {
#pragma unroll
    for (int dd = 0; dd < NDOM; ++dd)
      atomicAdd(&lcnt[dd], (unsigned)cnt[dd]);
  }
  __syncthreads();

  // block -> global: 16 coalesced f32 atomics per thread
  for (int i = tid; i < NDOM * NF4; i += 256) {
    const int dd = i >> 8;
    const int j  = i & 255;
    const int fg = dd * NFEAT + ftile * 256 + j;
    atomicAdd(&gsum[fg], lsum[dd][j]);
    atomicAdd(&gsq [fg], lsq [dd][j]);
  }
  if (ftile == 0 && tid < NDOM) atomicAdd(&gcnt[tid], lcnt[tid]);
}

__global__ __launch_bounds__(256) void dsbn_prep(
    const float* __restrict__ gsum, const float* __restrict__ gsq,
    const unsigned* __restrict__ gcnt,
    const float* __restrict__ gamma, const float* __restrict__ beta,
    float* __restrict__ scl, float* __restrict__ bia)
{
  const int i = blockIdx.x * 256 + threadIdx.x;   // 0..8191
  const int d = i >> 10;
  const int f = i & 1023;
  const float c    = (float)gcnt[d];
  const float sc   = fmaxf(c, 1.f);
  const float mean = gsum[i] / sc;
  float var = gsq[i] / sc - mean * mean;   // E[x^2]-mean^2; data ~N(0,1)
  var = fmaxf(var, 0.f);
  float scale, bias;
  if (c > 1.5f) {
    const float inv = 1.f / sqrtf(var + EPSV);
    scale = gamma[f] * inv;
    bias  = fmaf(-mean, scale, beta[f]);
  } else if (c > 0.5f) {   // count == 1 -> raw x
    scale = 1.f; bias = 0.f;
  } else {                 // count == 0 -> 0
    scale = 0.f; bias = 0.f;
  }
  scl[i] = scale;
  bia[i] = bias;
}

__global__ __launch_bounds__(256) void dsbn_norm(
    const float* __restrict__ x, const int* __restrict__ y,
    const float* __restrict__ scl, const float* __restrict__ bia,
    float* __restrict__ out)
{
  const float4* __restrict__ x4 = reinterpret_cast<const float4*>(x);
  const float4* __restrict__ s4 = reinterpret_cast<const float4*>(scl);
  const float4* __restrict__ b4 = reinterpret_cast<const float4*>(bia);
  float4* __restrict__ o4 = reinterpret_cast<float4*>(out);

  const int S = gridDim.x * 256;
  for (int idx = blockIdx.x * 256 + threadIdx.x; idx < BATCH * NF4; idx += S) {
    const int r = idx >> 8;          // row; wave-uniform (64-idx window
    const int c = idx & 255;         // never crosses a 256-aligned row)
    const int d = __builtin_amdgcn_readfirstlane(y[r]);
    const float4 v  = x4[idx];
    const float4 sc = s4[d * NF4 + c];
    const float4 bb = b4[d * NF4 + c];
    float4 o;
    o.x = fmaf(v.x, sc.x, bb.x);
    o.y = fmaf(v.y, sc.y, bb.y);
    o.z = fmaf(v.z, sc.z, bb.z);
    o.w = fmaf(v.w, sc.w, bb.w);
    o4[idx] = o;
  }
}

extern "C" void kernel_launch(void* const* d_in, const int* in_sizes, int n_in,
                              void* d_out, int out_size, void* d_ws, size_t ws_size,
                              hipStream_t stream) {
  const float* x     = (const float*)d_in[0];
  const int*   y     = (const int*)  d_in[1];
  const float* gamma = (const float*)d_in[2];
  const float* beta  = (const float*)d_in[3];
  float* out = (float*)d_out;

  float*    ws   = (float*)d_ws;
  float*    gsum = ws + WS_SUM;
  float*    gsq  = ws + WS_SQ;
  unsigned* gcnt = (unsigned*)(ws + WS_CNT);
  float*    scl  = ws + WS_SCL;
  float*    bia  = ws + WS_BIA;

  // ws is re-poisoned to 0xAA before every timed call -> zero accumulators
  hipMemsetAsync(ws, 0, WS_ZERO_BYTES, stream);

  dsbn_stats<<<dim3(1024), dim3(256), 0, stream>>>(x, y, gsum, gsq, gcnt);
  dsbn_prep <<<dim3(32),   dim3(256), 0, stream>>>(gsum, gsq, gcnt, gamma, beta, scl, bia);
  dsbn_norm <<<dim3(2048), dim3(256), 0, stream>>>(x, y, scl, bia, out);
}